// Round 2
// baseline (217.932 us; speedup 1.0000x reference)
//
#include <hip/hip_runtime.h>

// Box3dAttention: B=2, LQ=4096, d=256, heads=8, head_dim=32, 5x5=25 points,
// feature map 188x188 (LV=35344).
//
// Round 10 = round 9 +
//  (a) gemm_bf16: double-buffered LDS + stage-ahead schedule (issue kc+1
//      global loads BEFORE kc's MFMA section; A bf16-pack+ds_write AFTER the
//      MFMAs so its vmcnt wait is covered; ONE barrier per K-step, was two).
//  (b) gemm_bf16: T2 XOR-swizzle on As/Bs (granule col ^= row&7) applied
//      both-sides-consistently: global_load_lds keeps linear dest with
//      pre-swizzled per-lane global source; reg-staged A writes to the
//      swizzled granule; fragment ds_read_b128s apply the same XOR.
//      Fixes the 16-way bank conflict (3.4M conflict cycles in K1).
//
// Pipeline:
//  K0 convert    : W_value/W_out -> bf16, [W_attn;W_box] -> fp32 pad, bias pad
//  K1 gemm<1,1,128>: value fp32 (fused cvt) @ wvbf^T + b_value -> Vout bf16
//                    head-major [b*8+h][LV][32]
//  K2 gemm_nt    : fp32 VALU logits = query @ [W_attn;W_box]^T + b (box accuracy)
//  K3 decode_sample: block=(slice s=b*8+h, 8 q); XCD-temporal remap
//  K4 gemm<0,0,64>: ohbf @ wobf^T + b_out -> out fp32

typedef float floatx4 __attribute__((ext_vector_type(4)));
typedef short shortx8 __attribute__((ext_vector_type(8)));

static __device__ __forceinline__ unsigned short f2bf(float x) {
    unsigned int u = __float_as_uint(x);
    return (unsigned short)((u + 0x7fffu + ((u >> 16) & 1u)) >> 16);
}
static __device__ __forceinline__ unsigned int pack2(float a, float b) {
    return (unsigned int)f2bf(a) | ((unsigned int)f2bf(b) << 16);
}
static __device__ __forceinline__ void async16(const void* g, void* lds) {
    __builtin_amdgcn_global_load_lds(
        (const __attribute__((address_space(1))) unsigned int*)g,
        (__attribute__((address_space(3))) unsigned int*)lds, 16, 0, 0);
}

// ---------------- K0: weight/bias conversions only ----------------
// grid = 16 (W_value) + 16 (Wab fp32 pad) + 16 (W_out) + 1 (bias) = 49
__global__ __launch_bounds__(256) void convert_kernel(
    const float* __restrict__ W_value, unsigned short* __restrict__ wvbf,
    const float* __restrict__ W_attn, const float* __restrict__ W_box,
    float* __restrict__ Wab,
    const float* __restrict__ W_out, unsigned short* __restrict__ wobf,
    const float* __restrict__ b_attn, const float* __restrict__ b_box,
    float* __restrict__ bab)
{
    const int blk = blockIdx.x, tid = threadIdx.x;
    if (blk < 16) {
        int base = blk * 1024 + tid;
#pragma unroll
        for (int k = 0; k < 4; ++k) {
            int j = base + k * 256;
            float4 f = ((const float4*)W_value)[j];
            ((uint2*)wvbf)[j] = make_uint2(pack2(f.x, f.y), pack2(f.z, f.w));
        }
    } else if (blk < 32) {
        int base = (blk - 16) * 1024 + tid;
#pragma unroll
        for (int k = 0; k < 4; ++k) {
            int j = base + k * 256;
            int row = j >> 6, col = (j & 63) * 4;
            float4 f;
            if (row < 200)      f = *(const float4*)(W_attn + (size_t)row * 256 + col);
            else if (row < 240) f = *(const float4*)(W_box + (size_t)(row - 200) * 256 + col);
            else                f = make_float4(0.f, 0.f, 0.f, 0.f);
            ((float4*)Wab)[j] = f;
        }
    } else if (blk < 48) {
        int base = (blk - 32) * 1024 + tid;
#pragma unroll
        for (int k = 0; k < 4; ++k) {
            int j = base + k * 256;
            float4 f = ((const float4*)W_out)[j];
            ((uint2*)wobf)[j] = make_uint2(pack2(f.x, f.y), pack2(f.z, f.w));
        }
    } else {
        bab[tid] = tid < 200 ? b_attn[tid] : (tid < 240 ? b_box[tid - 200] : 0.f);
    }
}

// ---------------- bf16 MFMA GEMM (dbuf + stage-ahead + XOR-swizzle) ----------------
// C = A(M x 256) @ Bw(256 x 256 bf16)^T + bias
// AFP32=1: A fp32, converted in reg-staging (f2bf RNE), ds_write AFTER MFMAs.
// AFP32=0: A bf16 via global_load_lds. BM: M-tile (128 or 64). BN fixed 128.
// LDS granule swizzle: LDS(row, g) holds global(row, g ^ (row&7)); all reads
// apply the same XOR -> 16-way bank conflict eliminated.
// mfma(bfr, af, acc) => D^T layout: col(lane&15)=m, row(lq*4+r)=n.
// OUTMODE 0: C fp32 row-major [M][256]; OUTMODE 1: C bf16 head-major [b*8+h][LV][32]
template <int OUTMODE, int AFP32, int BM>
__global__ __launch_bounds__(256) void gemm_bf16(
    const void* __restrict__ Av,
    const unsigned short* __restrict__ Bw,
    const float* __restrict__ bias,
    void* __restrict__ Cv, int M, int LV)
{
    constexpr int NI = BM / 32;   // A staging row-blocks of 32
    constexpr int TI = BM / 32;   // ti tiles per wave (wave M-span = BM/2)
    __shared__ unsigned short As[2][BM * 64];
    __shared__ unsigned short Bs[2][128 * 64];
    const int tid = threadIdx.x;
    const int wv = tid >> 6, lane = tid & 63;
    const int lr = lane & 15, lq = lane >> 4;
    const int m0 = blockIdx.x * BM, n0 = blockIdx.y * 128;
    const int wm = wv & 1, wn = wv >> 1;
    const int srow = tid >> 3;                  // 0..31 within i-block
    const int colg = tid & 7;                   // granule col (16B granules)
    const int colgSw = colg ^ (srow & 7);       // swizzled granule col
    const int dstA = (srow * 8 + colgSw) * 16;  // swizzled byte off (reg-staged A)

    floatx4 acc[TI][4];
#pragma unroll
    for (int i = 0; i < TI; ++i)
#pragma unroll
        for (int j = 0; j < 4; ++j) acc[i][j] = (floatx4){0.f, 0.f, 0.f, 0.f};

    float4 ar0[NI], ar1[NI];   // in-flight fp32 A regs (AFP32 path)

    // ---------- prologue: stage kc=0 into buffer 0 ----------
    if constexpr (AFP32) {
        const float* Af = (const float*)Av;
#pragma unroll
        for (int i = 0; i < NI; ++i) {
            int ra = m0 + i * 32 + srow; ra = ra < M ? ra : M - 1;
            const float* ap = Af + (size_t)ra * 256 + colg * 8;
            ar0[i] = *(const float4*)ap;
            ar1[i] = *(const float4*)(ap + 4);
        }
    } else {
        const unsigned short* Ab = (const unsigned short*)Av;
#pragma unroll
        for (int i = 0; i < NI; ++i) {
            int ra = m0 + i * 32 + srow; ra = ra < M ? ra : M - 1;
            async16(Ab + (size_t)ra * 256 + colgSw * 8, (char*)As[0] + i * 4096 + wv * 1024);
        }
    }
#pragma unroll
    for (int i = 0; i < 4; ++i) {
        int rb = n0 + i * 32 + srow;
        async16(Bw + (size_t)rb * 256 + colgSw * 8, (char*)Bs[0] + i * 4096 + wv * 1024);
    }
    if constexpr (AFP32) {
#pragma unroll
        for (int i = 0; i < NI; ++i) {
            uint4 pv = make_uint4(pack2(ar0[i].x, ar0[i].y), pack2(ar0[i].z, ar0[i].w),
                                  pack2(ar1[i].x, ar1[i].y), pack2(ar1[i].z, ar1[i].w));
            *(uint4*)((char*)As[0] + i * 4096 + dstA) = pv;
        }
    }
    __syncthreads();

    int cur = 0;
    for (int kc = 0; kc < 4; ++kc) {
        const int nk = (kc + 1) * 64;
        // ---- issue next-tile loads FIRST (overlap with MFMA below) ----
        if (kc < 3) {
            if constexpr (AFP32) {
                const float* Af = (const float*)Av;
#pragma unroll
                for (int i = 0; i < NI; ++i) {
                    int ra = m0 + i * 32 + srow; ra = ra < M ? ra : M - 1;
                    const float* ap = Af + (size_t)ra * 256 + nk + colg * 8;
                    ar0[i] = *(const float4*)ap;
                    ar1[i] = *(const float4*)(ap + 4);
                }
            } else {
                const unsigned short* Ab = (const unsigned short*)Av;
#pragma unroll
                for (int i = 0; i < NI; ++i) {
                    int ra = m0 + i * 32 + srow; ra = ra < M ? ra : M - 1;
                    async16(Ab + (size_t)ra * 256 + nk + colgSw * 8,
                            (char*)As[cur ^ 1] + i * 4096 + wv * 1024);
                }
            }
#pragma unroll
            for (int i = 0; i < 4; ++i) {
                int rb = n0 + i * 32 + srow;
                async16(Bw + (size_t)rb * 256 + nk + colgSw * 8,
                        (char*)Bs[cur ^ 1] + i * 4096 + wv * 1024);
            }
        }
        // ---- compute current tile (swizzled fragment reads) ----
#pragma unroll
        for (int kb = 0; kb < 2; ++kb) {
            shortx8 af[TI], bfr[4];
#pragma unroll
            for (int t = 0; t < TI; ++t) {
                int arow = wm * (BM / 2) + t * 16 + lr;
                af[t] = *(const shortx8*)&As[cur][arow * 64 + (((kb * 4 + lq) ^ (arow & 7)) * 8)];
            }
#pragma unroll
            for (int t = 0; t < 4; ++t) {
                int brow = wn * 64 + t * 16 + lr;
                bfr[t] = *(const shortx8*)&Bs[cur][brow * 64 + (((kb * 4 + lq) ^ (brow & 7)) * 8)];
            }
#pragma unroll
            for (int ti = 0; ti < TI; ++ti)
#pragma unroll
                for (int tj = 0; tj < 4; ++tj)
                    acc[ti][tj] = __builtin_amdgcn_mfma_f32_16x16x32_bf16(bfr[tj], af[ti], acc[ti][tj], 0, 0, 0);
        }
        // ---- late A pack+write (fp32 load latency covered by MFMAs) ----
        if (kc < 3) {
            if constexpr (AFP32) {
#pragma unroll
                for (int i = 0; i < NI; ++i) {
                    uint4 pv = make_uint4(pack2(ar0[i].x, ar0[i].y), pack2(ar0[i].z, ar0[i].w),
                                          pack2(ar1[i].x, ar1[i].y), pack2(ar1[i].z, ar1[i].w));
                    *(uint4*)((char*)As[cur ^ 1] + i * 4096 + dstA) = pv;
                }
            }
        }
        __syncthreads();
        cur ^= 1;
    }
    // epilogue (transposed D): m = col = lr-indexed, n = row = lq*4 + reg
#pragma unroll
    for (int ti = 0; ti < TI; ++ti) {
        int m = m0 + wm * (BM / 2) + ti * 16 + lr;
        if (m >= M) continue;
        if (OUTMODE == 0) {
            float* Crow = (float*)Cv + (size_t)m * 256;
#pragma unroll
            for (int tj = 0; tj < 4; ++tj) {
                int nb = n0 + wn * 64 + tj * 16 + lq * 4;
                float4 bv = *(const float4*)(bias + nb);
                float4 o = make_float4(acc[ti][tj][0] + bv.x, acc[ti][tj][1] + bv.y,
                                       acc[ti][tj][2] + bv.z, acc[ti][tj][3] + bv.w);
                *(float4*)(Crow + nb) = o;
            }
        } else {
            int b = m >= LV ? 1 : 0;
            int lv = m - (b ? LV : 0);
#pragma unroll
            for (int tj = 0; tj < 4; ++tj) {
                int nb = n0 + wn * 64 + tj * 16 + lq * 4;
                float4 bv = *(const float4*)(bias + nb);
                int h = nb >> 5, dh = nb & 31;
                unsigned short* dst = (unsigned short*)Cv + ((size_t)(b * 8 + h) * LV + lv) * 32 + dh;
                *(uint2*)dst = make_uint2(pack2(acc[ti][tj][0] + bv.x, acc[ti][tj][1] + bv.y),
                                          pack2(acc[ti][tj][2] + bv.z, acc[ti][tj][3] + bv.w));
            }
        }
    }
}

// ---------------- K2: fp32 tiled GEMM (logits, accuracy-critical) ----------------
__global__ __launch_bounds__(256) void gemm_nt_bias(
    const float* __restrict__ A, const float* __restrict__ W,
    const float* __restrict__ bias, float* __restrict__ C, int M)
{
    const int K = 256, N = 256;
    __shared__ float As[16][68];
    __shared__ float Bs[16][68];
    int tid = threadIdx.x;
    int tcol = tid & 15, trow = tid >> 4;
    int m0 = blockIdx.x * 64, n0 = blockIdx.y * 64;
    int lr = tid >> 2, lc = (tid & 3) << 2;
    float acc[4][4] = {};
    for (int k0 = 0; k0 < K; k0 += 16) {
        int arow = m0 + lr; if (arow > M - 1) arow = M - 1;
        float4 av = *(const float4*)(A + (size_t)arow * K + k0 + lc);
        float4 wv = *(const float4*)(W + (size_t)(n0 + lr) * K + k0 + lc);
        __syncthreads();
        As[lc + 0][lr] = av.x; As[lc + 1][lr] = av.y; As[lc + 2][lr] = av.z; As[lc + 3][lr] = av.w;
        Bs[lc + 0][lr] = wv.x; Bs[lc + 1][lr] = wv.y; Bs[lc + 2][lr] = wv.z; Bs[lc + 3][lr] = wv.w;
        __syncthreads();
#pragma unroll
        for (int k = 0; k < 16; ++k) {
            float4 a4 = *(const float4*)&As[k][trow << 2];
            float4 b4 = *(const float4*)&Bs[k][tcol << 2];
            float a[4] = {a4.x, a4.y, a4.z, a4.w};
            float bb[4] = {b4.x, b4.y, b4.z, b4.w};
#pragma unroll
            for (int i = 0; i < 4; i++)
#pragma unroll
                for (int j = 0; j < 4; j++) acc[i][j] += a[i] * bb[j];
        }
    }
#pragma unroll
    for (int i = 0; i < 4; i++) {
        int m = m0 + trow * 4 + i;
        if (m >= M) continue;
#pragma unroll
        for (int j = 0; j < 4; j++) {
            int n = n0 + tcol * 4 + j;
            C[(size_t)m * N + n] = acc[i][j] + bias[n];
        }
    }
}

// ---------------- K3: XCD-temporal fused decode + bilinear gather ----------------
// grid (16, LQ/8). Linear block id lin = y*16+x round-robins XCDs (xcd=lin%8).
// Remap so XCD k processes slice k for c in [0,LQ/8), THEN slice k+8:
//   seq = lin>>3; c = seq % (LQ/8); s = (lin&7) + 8*(seq / (LQ/8)).
// Instantaneous per-XCD V working set: one 2.26 MB slice (< 4 MB L2).
__global__ __launch_bounds__(256) void decode_sample_kernel(
    const unsigned short* __restrict__ v,   // bf16 [b*8+h][LV][32]
    const float* __restrict__ logits,       // MQ x 256 (240 real)
    const float* __restrict__ ref_windows,  // MQ x 7
    float* __restrict__ attn_out,           // MQ x 200
    unsigned short* __restrict__ ohbf,      // MQ x 256 bf16
    const int* __restrict__ Hf_p, const int* __restrict__ Wf_p, int LV, int LQ)
{
    __shared__ float lg[8][32];
    __shared__ float rw[8][7];
    __shared__ float prm[8][6];
    __shared__ float mxinv[8][2];
    __shared__ uint4 pk[8][25][2];   // [q][point][colhalf] = {w_row0, w_row1, off0, off1}

    const int lin = blockIdx.y * 16 + blockIdx.x;
    const int nc = gridDim.y;               // LQ/8
    const int seq = lin >> 3;
    const int c = seq % nc;
    const int s = (lin & 7) + ((seq / nc) << 3);
    const int b = s >> 3, h = s & 7;
    const int tid = threadIdx.x;
    const int Hf = *Hf_p, Wf = *Wf_p;
    const size_t mbase = (size_t)b * LQ + c * 8;

    if (tid < 240) {
        int qq = tid / 30, j = tid - qq * 30;
        int col = (j < 25) ? h * 25 + j : 200 + h * 5 + (j - 25);
        lg[qq][j] = logits[(mbase + qq) * 256 + col];
    }
    // separate if (NOT else-if): only 256 threads in the block
    if (tid < 56) {
        int qq = tid / 7, k = tid - qq * 7;
        rw[qq][k] = ref_windows[(mbase + qq) * 7 + k];
    }
    __syncthreads();

    if (tid < 8) {
        int qq = tid;
        float mx = -1e30f;
#pragma unroll
        for (int p = 0; p < 25; p++) mx = fmaxf(mx, lg[qq][p]);
        float ssum = 0.f;
#pragma unroll
        for (int p = 0; p < 25; p++) ssum += expf(lg[qq][p] - mx);
        mxinv[qq][0] = mx; mxinv[qq][1] = 1.f / ssum;
        float cx = rw[qq][0] + lg[qq][25] * 0.125f * rw[qq][3];
        float cy = rw[qq][1] + lg[qq][26] * 0.125f * rw[qq][4];
        float bw = rw[qq][3] + lg[qq][27] * 0.125f * rw[qq][3];
        float bh = rw[qq][4] + lg[qq][28] * 0.125f * rw[qq][4];
        float ang = (rw[qq][6] + lg[qq][29] * 0.0625f) * 6.283185307179586f;
        prm[qq][0] = cx; prm[qq][1] = cy;
        prm[qq][2] = fmaxf(bw, 0.f); prm[qq][3] = fmaxf(bh, 0.f);
        prm[qq][4] = cosf(ang); prm[qq][5] = sinf(ang);
    }
    __syncthreads();

    if (tid < 200) {
        int qq = tid / 25, p = tid - qq * 25;
        float a = expf(lg[qq][p] - mxinv[qq][0]) * mxinv[qq][1];
        attn_out[(mbase + qq) * 200 + h * 25 + p] = a;
        int pi = p / 5, pj = p - pi * 5;
        float g0 = (float)(pj - 2) * 0.2f * prm[qq][2];
        float g1 = (float)(pi - 2) * 0.2f * prm[qq][3];
        float ca = prm[qq][4], sa = prm[qq][5];
        float gx = (prm[qq][0] + g0 * ca - g1 * sa) * (float)Wf - 0.5f;
        float gy = (prm[qq][1] + g0 * sa + g1 * ca) * (float)Hf - 0.5f;
        float x0f = floorf(gx), y0f = floorf(gy);
        int x0 = (int)x0f, y0 = (int)y0f;
        float wx1 = gx - x0f, wy1 = gy - y0f;
        float wx0 = 1.f - wx1, wy0 = 1.f - wy1;
        int y1 = y0 + 1;
        int bx; float wl, wr;
        if (x0 >= 0 && x0 <= Wf - 2)      { bx = x0;     wl = wx0; wr = wx1; }
        else if (x0 == -1)                { bx = 0;      wl = wx1; wr = 0.f; }
        else if (x0 == Wf - 1)            { bx = Wf - 2; wl = 0.f; wr = wx0; }
        else                              { bx = 0;      wl = 0.f; wr = 0.f; }
        float wy0v = (y0 >= 0 && y0 < Hf) ? wy0 : 0.f;
        float wy1v = (y1 >= 0 && y1 < Hf) ? wy1 : 0.f;
        int cy0 = min(max(y0, 0), Hf - 1), cy1 = min(max(y1, 0), Hf - 1);
        unsigned off0 = (unsigned)(cy0 * Wf + bx) * 16u;
        unsigned off1 = (unsigned)(cy1 * Wf + bx) * 16u;
        float aw0 = a * wy0v, aw1 = a * wy1v;
        pk[qq][p][0] = make_uint4(__float_as_uint(aw0 * wl), __float_as_uint(aw1 * wl), off0, off1);
        pk[qq][p][1] = make_uint4(__float_as_uint(aw0 * wr), __float_as_uint(aw1 * wr), off0, off1);
    }
    __syncthreads();

    const int qq = tid >> 5, l = tid & 31;
    const unsigned int* vw = (const unsigned int*)(v + (size_t)s * LV * 32);
    const uint4* pkp = &pk[qq][0][l >> 4];
    float e0 = 0.f, o0 = 0.f, e1 = 0.f, o1 = 0.f;
#pragma unroll
    for (int p = 0; p < 25; ++p) {
        uint4 t = pkp[2 * p];                 // ds_read_b128
        float w0 = __uint_as_float(t.x), w1 = __uint_as_float(t.y);
        unsigned u0 = vw[t.z + l];
        unsigned u1 = vw[t.w + l];
        e0 += w0 * __uint_as_float(u0 << 16);
        o0 += w0 * __uint_as_float(u0 & 0xffff0000u);
        e1 += w1 * __uint_as_float(u1 << 16);
        o1 += w1 * __uint_as_float(u1 & 0xffff0000u);
    }
    float a0 = e0 + e1, a1 = o0 + o1;
    a0 += __shfl_xor(a0, 16, 32);
    a1 += __shfl_xor(a1, 16, 32);
    if (l < 16)
        ((unsigned int*)ohbf)[(mbase + qq) * 128 + h * 16 + l] = pack2(a0, a1);
}

extern "C" void kernel_launch(void* const* d_in, const int* in_sizes, int n_in,
                              void* d_out, int out_size, void* d_ws, size_t ws_size,
                              hipStream_t stream) {
    const float* query       = (const float*)d_in[0];
    const float* value       = (const float*)d_in[1];
    const float* ref_windows = (const float*)d_in[2];
    const float* W_box       = (const float*)d_in[3];
    const float* b_box       = (const float*)d_in[4];
    const float* W_attn      = (const float*)d_in[5];
    const float* b_attn      = (const float*)d_in[6];
    const float* W_value     = (const float*)d_in[7];
    const float* b_value     = (const float*)d_in[8];
    const float* W_out       = (const float*)d_in[9];
    const float* b_out       = (const float*)d_in[10];
    const int*   Hf          = (const int*)d_in[11];
    const int*   Wf          = (const int*)d_in[12];

    const int M1 = in_sizes[1] / 256;  // B*LV = 70688
    const int MQ = in_sizes[0] / 256;  // B*LQ = 8192
    const int LQ = MQ / 2;
    const int LV = M1 / 2;

    unsigned short* Vout = (unsigned short*)d_ws;                 // M1*256
    unsigned short* ohbf = Vout + (size_t)M1 * 256;               // MQ*256
    unsigned short* wvbf = ohbf + (size_t)MQ * 256;               // 65536
    unsigned short* wobf = wvbf + 65536;                          // 65536
    float* Wab       = (float*)(wobf + 65536);                    // 65536 fp32
    float* bab       = Wab + 65536;                               // 256
    float* logits    = bab + 256;                                 // MQ*256

    float* out0     = (float*)d_out;
    float* attn_out = out0 + (size_t)MQ * 256;

    // K0: weight conversions (16 + 16 + 16 + 1 = 49 blocks)
    convert_kernel<<<49, 256, 0, stream>>>(W_value, wvbf, W_attn, W_box, Wab,
                                           W_out, wobf, b_attn, b_box, bab);
    // K1: value projection (fused fp32->bf16 A-staging) -> head-major bf16 Vout
    dim3 g1((M1 + 127) / 128, 2);
    gemm_bf16<1, 1, 128><<<g1, 256, 0, stream>>>(value, wvbf, b_value, Vout, M1, LV);
    // K2: logits fp32 (accuracy-critical box path)
    dim3 g2(MQ / 64, 4);
    gemm_nt_bias<<<g2, 256, 0, stream>>>(query, Wab, bab, logits, MQ);
    // K3: XCD-temporal fused softmax + box decode + gather -> bf16 out_heads
    decode_sample_kernel<<<dim3(16, LQ / 8), 256, 0, stream>>>(
        Vout, logits, ref_windows, attn_out, ohbf, Hf, Wf, LV, LQ);
    // K4: output projection via bf16 MFMA (BM=64 -> 256 blocks, full CU coverage)
    dim3 g4(MQ / 64, 2);
    gemm_bf16<0, 0, 64><<<g4, 256, 0, stream>>>(ohbf, wobf, b_out, out0, MQ, LV);
}

// Round 3
// 212.375 us; speedup vs baseline: 1.0262x; 1.0262x over previous
//
#include <hip/hip_runtime.h>

// Box3dAttention: B=2, LQ=4096, d=256, heads=8, head_dim=32, 5x5=25 points,
// feature map 188x188 (LV=35344).
//
// Round 11 = round 10 +
//  (a) gemm_bf16<AFP32=1> (K1): hand-scheduled software pipeline — fully
//      unrolled 4-step K-loop with counted s_waitcnt vmcnt(8) (never 0 while
//      A-prefetch in flight), raw s_barrier, and sched_barrier(0) pinning so
//      the compiler cannot sink the A global-loads to their use (round-10
//      VGPR=92 proved it did: 8 float4 loads = 32 VGPRs were NOT live across
//      the MFMA section). A-loads for step k+2 stay in flight ACROSS the
//      barrier; only B (L2-resident weights) is drained per step.
//  (b) K4 keeps the plain dbuf+__syncthreads path (small, L2-hot inputs).
//
// Pipeline:
//  K0 convert    : W_value/W_out -> bf16, [W_attn;W_box] -> fp32 pad, bias pad
//  K1 gemm<1,1,128>: value fp32 (fused cvt) @ wvbf^T + b_value -> Vout bf16
//                    head-major [b*8+h][LV][32]
//  K2 gemm_nt    : fp32 VALU logits = query @ [W_attn;W_box]^T + b (box accuracy)
//  K3 decode_sample: block=(slice s=b*8+h, 8 q); XCD-temporal remap
//  K4 gemm<0,0,64>: ohbf @ wobf^T + b_out -> out fp32

typedef float floatx4 __attribute__((ext_vector_type(4)));
typedef short shortx8 __attribute__((ext_vector_type(8)));

#define SB0 __builtin_amdgcn_sched_barrier(0)
#define VMCNT8 asm volatile("s_waitcnt vmcnt(8)" ::: "memory")
#define VMCNT0 asm volatile("s_waitcnt vmcnt(0)" ::: "memory")
#define LGKM0  asm volatile("s_waitcnt lgkmcnt(0)" ::: "memory")

static __device__ __forceinline__ unsigned short f2bf(float x) {
    unsigned int u = __float_as_uint(x);
    return (unsigned short)((u + 0x7fffu + ((u >> 16) & 1u)) >> 16);
}
static __device__ __forceinline__ unsigned int pack2(float a, float b) {
    return (unsigned int)f2bf(a) | ((unsigned int)f2bf(b) << 16);
}
static __device__ __forceinline__ void async16(const void* g, void* lds) {
    __builtin_amdgcn_global_load_lds(
        (const __attribute__((address_space(1))) unsigned int*)g,
        (__attribute__((address_space(3))) unsigned int*)lds, 16, 0, 0);
}

// ---------------- K0: weight/bias conversions only ----------------
// grid = 16 (W_value) + 16 (Wab fp32 pad) + 16 (W_out) + 1 (bias) = 49
__global__ __launch_bounds__(256) void convert_kernel(
    const float* __restrict__ W_value, unsigned short* __restrict__ wvbf,
    const float* __restrict__ W_attn, const float* __restrict__ W_box,
    float* __restrict__ Wab,
    const float* __restrict__ W_out, unsigned short* __restrict__ wobf,
    const float* __restrict__ b_attn, const float* __restrict__ b_box,
    float* __restrict__ bab)
{
    const int blk = blockIdx.x, tid = threadIdx.x;
    if (blk < 16) {
        int base = blk * 1024 + tid;
#pragma unroll
        for (int k = 0; k < 4; ++k) {
            int j = base + k * 256;
            float4 f = ((const float4*)W_value)[j];
            ((uint2*)wvbf)[j] = make_uint2(pack2(f.x, f.y), pack2(f.z, f.w));
        }
    } else if (blk < 32) {
        int base = (blk - 16) * 1024 + tid;
#pragma unroll
        for (int k = 0; k < 4; ++k) {
            int j = base + k * 256;
            int row = j >> 6, col = (j & 63) * 4;
            float4 f;
            if (row < 200)      f = *(const float4*)(W_attn + (size_t)row * 256 + col);
            else if (row < 240) f = *(const float4*)(W_box + (size_t)(row - 200) * 256 + col);
            else                f = make_float4(0.f, 0.f, 0.f, 0.f);
            ((float4*)Wab)[j] = f;
        }
    } else if (blk < 48) {
        int base = (blk - 32) * 1024 + tid;
#pragma unroll
        for (int k = 0; k < 4; ++k) {
            int j = base + k * 256;
            float4 f = ((const float4*)W_out)[j];
            ((uint2*)wobf)[j] = make_uint2(pack2(f.x, f.y), pack2(f.z, f.w));
        }
    } else {
        bab[tid] = tid < 200 ? b_attn[tid] : (tid < 240 ? b_box[tid - 200] : 0.f);
    }
}

// ---------------- bf16 MFMA GEMM ----------------
// C = A(M x 256) @ Bw(256 x 256 bf16)^T + bias
// AFP32=1 (K1): hand-scheduled pipeline, counted vmcnt + raw barriers.
// AFP32=0 (K4): plain dbuf + __syncthreads.
// LDS granule swizzle: LDS(row, g) holds global(row, g ^ (row&7)).
// mfma(bfr, af, acc) => D^T layout: col(lane&15)=m, row(lq*4+r)=n.
// OUTMODE 0: C fp32 row-major [M][256]; OUTMODE 1: C bf16 head-major [b*8+h][LV][32]
template <int OUTMODE, int AFP32, int BM>
__global__ __launch_bounds__(256) void gemm_bf16(
    const void* __restrict__ Av,
    const unsigned short* __restrict__ Bw,
    const float* __restrict__ bias,
    void* __restrict__ Cv, int M, int LV)
{
    constexpr int NI = BM / 32;   // A staging row-blocks of 32
    constexpr int TI = BM / 32;   // ti tiles per wave (wave M-span = BM/2)
    __shared__ unsigned short As[2][BM * 64];
    __shared__ unsigned short Bs[2][128 * 64];
    const int tid = threadIdx.x;
    const int wv = tid >> 6, lane = tid & 63;
    const int lr = lane & 15, lq = lane >> 4;
    const int m0 = blockIdx.x * BM, n0 = blockIdx.y * 128;
    const int wm = wv & 1, wn = wv >> 1;
    const int srow = tid >> 3;                  // 0..31 within i-block
    const int colg = tid & 7;                   // granule col (16B granules)
    const int colgSw = colg ^ (srow & 7);       // swizzled granule col
    const int dstA = (srow * 8 + colgSw) * 16;  // swizzled byte off (reg-staged A)

    floatx4 acc[TI][4];
#pragma unroll
    for (int i = 0; i < TI; ++i)
#pragma unroll
        for (int j = 0; j < 4; ++j) acc[i][j] = (floatx4){0.f, 0.f, 0.f, 0.f};

    // fragment compute on buffer (Acur, Bcur)
    auto compute = [&](const unsigned short* Acur, const unsigned short* Bcur) {
#pragma unroll
        for (int kb = 0; kb < 2; ++kb) {
            shortx8 af[TI], bfr[4];
#pragma unroll
            for (int t = 0; t < TI; ++t) {
                int arow = wm * (BM / 2) + t * 16 + lr;
                af[t] = *(const shortx8*)&Acur[arow * 64 + (((kb * 4 + lq) ^ (arow & 7)) * 8)];
            }
#pragma unroll
            for (int t = 0; t < 4; ++t) {
                int brow = wn * 64 + t * 16 + lr;
                bfr[t] = *(const shortx8*)&Bcur[brow * 64 + (((kb * 4 + lq) ^ (brow & 7)) * 8)];
            }
#pragma unroll
            for (int ti = 0; ti < TI; ++ti)
#pragma unroll
                for (int tj = 0; tj < 4; ++tj)
                    acc[ti][tj] = __builtin_amdgcn_mfma_f32_16x16x32_bf16(bfr[tj], af[ti], acc[ti][tj], 0, 0, 0);
        }
    };

    if constexpr (AFP32) {
        // ---------- K1: hand-scheduled 4-step pipeline ----------
        const float* Af = (const float*)Av;
        const float* aptr[NI];
#pragma unroll
        for (int i = 0; i < NI; ++i) {
            int ra = m0 + i * 32 + srow; ra = ra < M ? ra : M - 1;
            aptr[i] = Af + (size_t)ra * 256 + colg * 8;
        }
        const unsigned short* bptr = Bw + (size_t)(n0 + srow) * 256 + colgSw * 8;
        float4 ar0[NI], ar1[NI];

        // prologue: A_0 -> regs, B_0 -> LDS, pack A_0, issue A_1, drain B_0
#pragma unroll
        for (int i = 0; i < NI; ++i) { ar0[i] = *(const float4*)aptr[i]; ar1[i] = *(const float4*)(aptr[i] + 4); }
#pragma unroll
        for (int i = 0; i < 4; ++i)
            async16(bptr + (size_t)i * 8192, (char*)Bs[0] + i * 4096 + wv * 1024);
        SB0;
#pragma unroll
        for (int i = 0; i < NI; ++i) {   // compiler inserts the A_0 wait here
            uint4 pv = make_uint4(pack2(ar0[i].x, ar0[i].y), pack2(ar0[i].z, ar0[i].w),
                                  pack2(ar1[i].x, ar1[i].y), pack2(ar1[i].z, ar1[i].w));
            *(uint4*)((char*)As[0] + i * 4096 + dstA) = pv;
        }
#pragma unroll
        for (int i = 0; i < NI; ++i) { ar0[i] = *(const float4*)(aptr[i] + 64); ar1[i] = *(const float4*)(aptr[i] + 68); }
        SB0;
        VMCNT8;        // B_0 retired; A_1 (8) stays in flight
        LGKM0;
        __builtin_amdgcn_s_barrier();
        SB0;

#pragma unroll
        for (int kc = 0; kc < 4; ++kc) {
            const int cur = kc & 1;
            // issue B_{kc+1} into Bs[cur^1] (L2-resident weights, MFMA covers)
            if (kc < 3) {
#pragma unroll
                for (int i = 0; i < 4; ++i)
                    async16(bptr + (size_t)i * 8192 + (kc + 1) * 64,
                            (char*)Bs[cur ^ 1] + i * 4096 + wv * 1024);
            }
            SB0;
            compute(As[cur], Bs[cur]);
            SB0;
            if (kc < 3) {
                // pack A_{kc+1} (compiler auto-waits the reg loads) -> As[cur^1]
#pragma unroll
                for (int i = 0; i < NI; ++i) {
                    uint4 pv = make_uint4(pack2(ar0[i].x, ar0[i].y), pack2(ar0[i].z, ar0[i].w),
                                          pack2(ar1[i].x, ar1[i].y), pack2(ar1[i].z, ar1[i].w));
                    *(uint4*)((char*)As[cur ^ 1] + i * 4096 + dstA) = pv;
                }
                if (kc < 2) {
                    // issue A_{kc+2}; stays in flight across the barrier
#pragma unroll
                    for (int i = 0; i < NI; ++i) {
                        ar0[i] = *(const float4*)(aptr[i] + (kc + 2) * 64);
                        ar1[i] = *(const float4*)(aptr[i] + (kc + 2) * 64 + 4);
                    }
                    SB0;
                    VMCNT8;   // retire B_{kc+1} only
                } else {
                    SB0;
                    VMCNT0;   // last prefetch step: retire B_3
                }
                LGKM0;
                __builtin_amdgcn_s_barrier();
                SB0;
            }
        }
    } else {
        // ---------- K4: plain dbuf + __syncthreads ----------
        const unsigned short* Ab = (const unsigned short*)Av;
#pragma unroll
        for (int i = 0; i < NI; ++i) {
            int ra = m0 + i * 32 + srow; ra = ra < M ? ra : M - 1;
            async16(Ab + (size_t)ra * 256 + colgSw * 8, (char*)As[0] + i * 4096 + wv * 1024);
        }
#pragma unroll
        for (int i = 0; i < 4; ++i) {
            int rb = n0 + i * 32 + srow;
            async16(Bw + (size_t)rb * 256 + colgSw * 8, (char*)Bs[0] + i * 4096 + wv * 1024);
        }
        __syncthreads();
        int cur = 0;
        for (int kc = 0; kc < 4; ++kc) {
            const int nk = (kc + 1) * 64;
            if (kc < 3) {
#pragma unroll
                for (int i = 0; i < NI; ++i) {
                    int ra = m0 + i * 32 + srow; ra = ra < M ? ra : M - 1;
                    async16(Ab + (size_t)ra * 256 + nk + colgSw * 8,
                            (char*)As[cur ^ 1] + i * 4096 + wv * 1024);
                }
#pragma unroll
                for (int i = 0; i < 4; ++i) {
                    int rb = n0 + i * 32 + srow;
                    async16(Bw + (size_t)rb * 256 + nk + colgSw * 8,
                            (char*)Bs[cur ^ 1] + i * 4096 + wv * 1024);
                }
            }
            compute(As[cur], Bs[cur]);
            __syncthreads();
            cur ^= 1;
        }
    }

    // epilogue (transposed D): m = col = lr-indexed, n = row = lq*4 + reg
#pragma unroll
    for (int ti = 0; ti < TI; ++ti) {
        int m = m0 + wm * (BM / 2) + ti * 16 + lr;
        if (m >= M) continue;
        if (OUTMODE == 0) {
            float* Crow = (float*)Cv + (size_t)m * 256;
#pragma unroll
            for (int tj = 0; tj < 4; ++tj) {
                int nb = n0 + wn * 64 + tj * 16 + lq * 4;
                float4 bv = *(const float4*)(bias + nb);
                float4 o = make_float4(acc[ti][tj][0] + bv.x, acc[ti][tj][1] + bv.y,
                                       acc[ti][tj][2] + bv.z, acc[ti][tj][3] + bv.w);
                *(float4*)(Crow + nb) = o;
            }
        } else {
            int b = m >= LV ? 1 : 0;
            int lv = m - (b ? LV : 0);
#pragma unroll
            for (int tj = 0; tj < 4; ++tj) {
                int nb = n0 + wn * 64 + tj * 16 + lq * 4;
                float4 bv = *(const float4*)(bias + nb);
                int h = nb >> 5, dh = nb & 31;
                unsigned short* dst = (unsigned short*)Cv + ((size_t)(b * 8 + h) * LV + lv) * 32 + dh;
                *(uint2*)dst = make_uint2(pack2(acc[ti][tj][0] + bv.x, acc[ti][tj][1] + bv.y),
                                          pack2(acc[ti][tj][2] + bv.z, acc[ti][tj][3] + bv.w));
            }
        }
    }
}

// ---------------- K2: fp32 tiled GEMM (logits, accuracy-critical) ----------------
__global__ __launch_bounds__(256) void gemm_nt_bias(
    const float* __restrict__ A, const float* __restrict__ W,
    const float* __restrict__ bias, float* __restrict__ C, int M)
{
    const int K = 256, N = 256;
    __shared__ float As[16][68];
    __shared__ float Bs[16][68];
    int tid = threadIdx.x;
    int tcol = tid & 15, trow = tid >> 4;
    int m0 = blockIdx.x * 64, n0 = blockIdx.y * 64;
    int lr = tid >> 2, lc = (tid & 3) << 2;
    float acc[4][4] = {};
    for (int k0 = 0; k0 < K; k0 += 16) {
        int arow = m0 + lr; if (arow > M - 1) arow = M - 1;
        float4 av = *(const float4*)(A + (size_t)arow * K + k0 + lc);
        float4 wv = *(const float4*)(W + (size_t)(n0 + lr) * K + k0 + lc);
        __syncthreads();
        As[lc + 0][lr] = av.x; As[lc + 1][lr] = av.y; As[lc + 2][lr] = av.z; As[lc + 3][lr] = av.w;
        Bs[lc + 0][lr] = wv.x; Bs[lc + 1][lr] = wv.y; Bs[lc + 2][lr] = wv.z; Bs[lc + 3][lr] = wv.w;
        __syncthreads();
#pragma unroll
        for (int k = 0; k < 16; ++k) {
            float4 a4 = *(const float4*)&As[k][trow << 2];
            float4 b4 = *(const float4*)&Bs[k][tcol << 2];
            float a[4] = {a4.x, a4.y, a4.z, a4.w};
            float bb[4] = {b4.x, b4.y, b4.z, b4.w};
#pragma unroll
            for (int i = 0; i < 4; i++)
#pragma unroll
                for (int j = 0; j < 4; j++) acc[i][j] += a[i] * bb[j];
        }
    }
#pragma unroll
    for (int i = 0; i < 4; i++) {
        int m = m0 + trow * 4 + i;
        if (m >= M) continue;
#pragma unroll
        for (int j = 0; j < 4; j++) {
            int n = n0 + tcol * 4 + j;
            C[(size_t)m * N + n] = acc[i][j] + bias[n];
        }
    }
}

// ---------------- K3: XCD-temporal fused decode + bilinear gather ----------------
// grid (16, LQ/8). Linear block id lin = y*16+x round-robins XCDs (xcd=lin%8).
// Remap so XCD k processes slice k for c in [0,LQ/8), THEN slice k+8:
//   seq = lin>>3; c = seq % (LQ/8); s = (lin&7) + 8*(seq / (LQ/8)).
// Instantaneous per-XCD V working set: one 2.26 MB slice (< 4 MB L2).
__global__ __launch_bounds__(256) void decode_sample_kernel(
    const unsigned short* __restrict__ v,   // bf16 [b*8+h][LV][32]
    const float* __restrict__ logits,       // MQ x 256 (240 real)
    const float* __restrict__ ref_windows,  // MQ x 7
    float* __restrict__ attn_out,           // MQ x 200
    unsigned short* __restrict__ ohbf,      // MQ x 256 bf16
    const int* __restrict__ Hf_p, const int* __restrict__ Wf_p, int LV, int LQ)
{
    __shared__ float lg[8][32];
    __shared__ float rw[8][7];
    __shared__ float prm[8][6];
    __shared__ float mxinv[8][2];
    __shared__ uint4 pk[8][25][2];   // [q][point][colhalf] = {w_row0, w_row1, off0, off1}

    const int lin = blockIdx.y * 16 + blockIdx.x;
    const int nc = gridDim.y;               // LQ/8
    const int seq = lin >> 3;
    const int c = seq % nc;
    const int s = (lin & 7) + ((seq / nc) << 3);
    const int b = s >> 3, h = s & 7;
    const int tid = threadIdx.x;
    const int Hf = *Hf_p, Wf = *Wf_p;
    const size_t mbase = (size_t)b * LQ + c * 8;

    if (tid < 240) {
        int qq = tid / 30, j = tid - qq * 30;
        int col = (j < 25) ? h * 25 + j : 200 + h * 5 + (j - 25);
        lg[qq][j] = logits[(mbase + qq) * 256 + col];
    }
    // separate if (NOT else-if): only 256 threads in the block
    if (tid < 56) {
        int qq = tid / 7, k = tid - qq * 7;
        rw[qq][k] = ref_windows[(mbase + qq) * 7 + k];
    }
    __syncthreads();

    if (tid < 8) {
        int qq = tid;
        float mx = -1e30f;
#pragma unroll
        for (int p = 0; p < 25; p++) mx = fmaxf(mx, lg[qq][p]);
        float ssum = 0.f;
#pragma unroll
        for (int p = 0; p < 25; p++) ssum += expf(lg[qq][p] - mx);
        mxinv[qq][0] = mx; mxinv[qq][1] = 1.f / ssum;
        float cx = rw[qq][0] + lg[qq][25] * 0.125f * rw[qq][3];
        float cy = rw[qq][1] + lg[qq][26] * 0.125f * rw[qq][4];
        float bw = rw[qq][3] + lg[qq][27] * 0.125f * rw[qq][3];
        float bh = rw[qq][4] + lg[qq][28] * 0.125f * rw[qq][4];
        float ang = (rw[qq][6] + lg[qq][29] * 0.0625f) * 6.283185307179586f;
        prm[qq][0] = cx; prm[qq][1] = cy;
        prm[qq][2] = fmaxf(bw, 0.f); prm[qq][3] = fmaxf(bh, 0.f);
        prm[qq][4] = cosf(ang); prm[qq][5] = sinf(ang);
    }
    __syncthreads();

    if (tid < 200) {
        int qq = tid / 25, p = tid - qq * 25;
        float a = expf(lg[qq][p] - mxinv[qq][0]) * mxinv[qq][1];
        attn_out[(mbase + qq) * 200 + h * 25 + p] = a;
        int pi = p / 5, pj = p - pi * 5;
        float g0 = (float)(pj - 2) * 0.2f * prm[qq][2];
        float g1 = (float)(pi - 2) * 0.2f * prm[qq][3];
        float ca = prm[qq][4], sa = prm[qq][5];
        float gx = (prm[qq][0] + g0 * ca - g1 * sa) * (float)Wf - 0.5f;
        float gy = (prm[qq][1] + g0 * sa + g1 * ca) * (float)Hf - 0.5f;
        float x0f = floorf(gx), y0f = floorf(gy);
        int x0 = (int)x0f, y0 = (int)y0f;
        float wx1 = gx - x0f, wy1 = gy - y0f;
        float wx0 = 1.f - wx1, wy0 = 1.f - wy1;
        int y1 = y0 + 1;
        int bx; float wl, wr;
        if (x0 >= 0 && x0 <= Wf - 2)      { bx = x0;     wl = wx0; wr = wx1; }
        else if (x0 == -1)                { bx = 0;      wl = wx1; wr = 0.f; }
        else if (x0 == Wf - 1)            { bx = Wf - 2; wl = 0.f; wr = wx0; }
        else                              { bx = 0;      wl = 0.f; wr = 0.f; }
        float wy0v = (y0 >= 0 && y0 < Hf) ? wy0 : 0.f;
        float wy1v = (y1 >= 0 && y1 < Hf) ? wy1 : 0.f;
        int cy0 = min(max(y0, 0), Hf - 1), cy1 = min(max(y1, 0), Hf - 1);
        unsigned off0 = (unsigned)(cy0 * Wf + bx) * 16u;
        unsigned off1 = (unsigned)(cy1 * Wf + bx) * 16u;
        float aw0 = a * wy0v, aw1 = a * wy1v;
        pk[qq][p][0] = make_uint4(__float_as_uint(aw0 * wl), __float_as_uint(aw1 * wl), off0, off1);
        pk[qq][p][1] = make_uint4(__float_as_uint(aw0 * wr), __float_as_uint(aw1 * wr), off0, off1);
    }
    __syncthreads();

    const int qq = tid >> 5, l = tid & 31;
    const unsigned int* vw = (const unsigned int*)(v + (size_t)s * LV * 32);
    const uint4* pkp = &pk[qq][0][l >> 4];
    float e0 = 0.f, o0 = 0.f, e1 = 0.f, o1 = 0.f;
#pragma unroll
    for (int p = 0; p < 25; ++p) {
        uint4 t = pkp[2 * p];                 // ds_read_b128
        float w0 = __uint_as_float(t.x), w1 = __uint_as_float(t.y);
        unsigned u0 = vw[t.z + l];
        unsigned u1 = vw[t.w + l];
        e0 += w0 * __uint_as_float(u0 << 16);
        o0 += w0 * __uint_as_float(u0 & 0xffff0000u);
        e1 += w1 * __uint_as_float(u1 << 16);
        o1 += w1 * __uint_as_float(u1 & 0xffff0000u);
    }
    float a0 = e0 + e1, a1 = o0 + o1;
    a0 += __shfl_xor(a0, 16, 32);
    a1 += __shfl_xor(a1, 16, 32);
    if (l < 16)
        ((unsigned int*)ohbf)[(mbase + qq) * 128 + h * 16 + l] = pack2(a0, a1);
}

extern "C" void kernel_launch(void* const* d_in, const int* in_sizes, int n_in,
                              void* d_out, int out_size, void* d_ws, size_t ws_size,
                              hipStream_t stream) {
    const float* query       = (const float*)d_in[0];
    const float* value       = (const float*)d_in[1];
    const float* ref_windows = (const float*)d_in[2];
    const float* W_box       = (const float*)d_in[3];
    const float* b_box       = (const float*)d_in[4];
    const float* W_attn      = (const float*)d_in[5];
    const float* b_attn      = (const float*)d_in[6];
    const float* W_value     = (const float*)d_in[7];
    const float* b_value     = (const float*)d_in[8];
    const float* W_out       = (const float*)d_in[9];
    const float* b_out       = (const float*)d_in[10];
    const int*   Hf          = (const int*)d_in[11];
    const int*   Wf          = (const int*)d_in[12];

    const int M1 = in_sizes[1] / 256;  // B*LV = 70688
    const int MQ = in_sizes[0] / 256;  // B*LQ = 8192
    const int LQ = MQ / 2;
    const int LV = M1 / 2;

    unsigned short* Vout = (unsigned short*)d_ws;                 // M1*256
    unsigned short* ohbf = Vout + (size_t)M1 * 256;               // MQ*256
    unsigned short* wvbf = ohbf + (size_t)MQ * 256;               // 65536
    unsigned short* wobf = wvbf + 65536;                          // 65536
    float* Wab       = (float*)(wobf + 65536);                    // 65536 fp32
    float* bab       = Wab + 65536;                               // 256
    float* logits    = bab + 256;                                 // MQ*256

    float* out0     = (float*)d_out;
    float* attn_out = out0 + (size_t)MQ * 256;

    // K0: weight conversions (16 + 16 + 16 + 1 = 49 blocks)
    convert_kernel<<<49, 256, 0, stream>>>(W_value, wvbf, W_attn, W_box, Wab,
                                           W_out, wobf, b_attn, b_box, bab);
    // K1: value projection (fused fp32->bf16 A-staging) -> head-major bf16 Vout
    dim3 g1((M1 + 127) / 128, 2);
    gemm_bf16<1, 1, 128><<<g1, 256, 0, stream>>>(value, wvbf, b_value, Vout, M1, LV);
    // K2: logits fp32 (accuracy-critical box path)
    dim3 g2(MQ / 64, 4);
    gemm_nt_bias<<<g2, 256, 0, stream>>>(query, Wab, bab, logits, MQ);
    // K3: XCD-temporal fused softmax + box decode + gather -> bf16 out_heads
    decode_sample_kernel<<<dim3(16, LQ / 8), 256, 0, stream>>>(
        Vout, logits, ref_windows, attn_out, ohbf, Hf, Wf, LV, LQ);
    // K4: output projection via bf16 MFMA (BM=64 -> 256 blocks, full CU coverage)
    dim3 g4(MQ / 64, 2);
    gemm_bf16<0, 0, 64><<<g4, 256, 0, stream>>>(ohbf, wobf, b_out, out0, MQ, LV);
}